// Round 12
// baseline (1543.492 us; speedup 1.0000x reference)
//
// ===========================================================================
// R12 — VQ: dims-split lanes (16 dims/lane in regs, no spill), padded LDS
// stride 68 (bank-conflict-free), subtract-form distances, commutative
// cross-lane combine. Convs: TL=128 tiles where LDS fits (TLT=16).
// Conv accumulation order unchanged vs R10/R11 (bit-identical conv outputs).
// ===========================================================================
#include <hip/hip_runtime.h>
#include <hip/hip_bf16.h>
#include <stdint.h>

// ---------------------------------------------------------------------------
// Tiled conv. MODE 0: stride-1 (pad runtime), WT=true: ConvTranspose (I,O,K)
// flipped. MODE 1: stride-2 downsample K=2. MODE 2: stride-2 transposed
// upsample K=2. Block: 256 thr = COB co x LT(=256/COB) l-groups, TLT=TL/LT
// outputs/thread. Per-output accumulation: ci-major, k-inner.
// ---------------------------------------------------------------------------
template<int CI, int CO, int K, int MODE, int TL, int COB,
         bool WT, bool STATS, bool HAS_BIAS, bool HAS_ADD>
__global__ __launch_bounds__(256)
void conv_rC(const float* __restrict__ xin,
             const float* __restrict__ w,
             const float* __restrict__ bias,
             const float* __restrict__ addsrc,
             double* __restrict__ stats,
             float* __restrict__ yout,
             int Lin, int Lout, int pad)
{
    constexpr int LT   = 256 / COB;
    constexpr int TLT  = TL / LT;
    constexpr int SPAN = (MODE == 0) ? (TL + K - 1)
                       : (MODE == 1) ? ((TL - 1) * 2 + K)
                       : (TL / 2);
    constexpr int SPANP = (SPAN + 3) & ~3;
    constexpr int WN    = COB * CI * K;

    __shared__ float xs[CI * SPANP];
    __shared__ float wl[WN];   // [ci][k][co_l]

    const int tid    = threadIdx.x;
    const int ltile  = blockIdx.x;
    const int n      = blockIdx.y;
    const int coBase = blockIdx.z * COB;

    for (int i = tid; i < WN; i += 256) {
        int ci   = i / (K * COB);
        int rem  = i - ci * (K * COB);
        int k    = rem / COB;
        int co_l = rem - k * COB;
        int co   = coBase + co_l;
        int src;
        if (WT)             src = (ci * CO + co) * K + (K - 1 - k);
        else if (MODE == 2) src = (ci * CO + co) * K + k;
        else                src = (co * CI + ci) * K + k;
        wl[i] = w[src];
    }

    int x0;
    if (MODE == 0)      x0 = ltile * TL - pad;
    else if (MODE == 1) x0 = ltile * TL * 2;
    else                x0 = ltile * (TL / 2);
    for (int i = tid; i < CI * SPAN; i += 256) {
        int ci = i / SPAN;
        int s  = i - ci * SPAN;
        int xl = x0 + s;
        float v = 0.f;
        if (xl >= 0 && xl < Lin) v = xin[((size_t)n * CI + ci) * Lin + xl];
        xs[ci * SPANP + s] = v;
    }
    __syncthreads();

    const int co_l  = tid / LT;
    const int co    = coBase + co_l;
    const int loOff = (tid % LT) * TLT;

    float acc[TLT];
#pragma unroll
    for (int j = 0; j < TLT; ++j) acc[j] = HAS_BIAS ? bias[co] : 0.f;

    constexpr int XR = (MODE == 0) ? (TLT + K - 1)
                     : (MODE == 1) ? ((TLT - 1) * 2 + K)
                     : (TLT / 2);

    for (int ci = 0; ci < CI; ++ci) {
        float xr[XR];
        const int xb = ci * SPANP + ((MODE == 1) ? loOff * 2
                                   : (MODE == 2) ? (loOff / 2) : loOff);
#pragma unroll
        for (int t = 0; t < XR; ++t) xr[t] = xs[xb + t];
        if (MODE == 2) {
            float w0 = wl[(ci * 2 + 0) * COB + co_l];
            float w1 = wl[(ci * 2 + 1) * COB + co_l];
#pragma unroll
            for (int j = 0; j < TLT; ++j)
                acc[j] += ((j & 1) ? w1 : w0) * xr[j >> 1];
        } else {
#pragma unroll
            for (int k = 0; k < K; ++k) {
                float wk = wl[(ci * K + k) * COB + co_l];
#pragma unroll
                for (int j = 0; j < TLT; ++j)
                    acc[j] += wk * xr[((MODE == 1) ? 2 * j : j) + k];
            }
        }
    }

    const int lo0   = ltile * TL + loOff;
    const size_t obase = ((size_t)n * CO + co) * Lout + lo0;

    if (HAS_ADD) {
#pragma unroll
        for (int j = 0; j < TLT; ++j) acc[j] += addsrc[obase + j];
    }

#pragma unroll
    for (int j = 0; j < TLT; ++j) yout[obase + j] = acc[j];

    if (STATS) {
        float s1 = 0.f, s2 = 0.f;
#pragma unroll
        for (int j = 0; j < TLT; ++j) { s1 += acc[j]; s2 += acc[j] * acc[j]; }
#pragma unroll
        for (int m = 1; m < LT; m <<= 1) {
            s1 += __shfl_xor(s1, m, 64);
            s2 += __shfl_xor(s2, m, 64);
        }
        if ((tid & (LT - 1)) == 0) {
            atomicAdd(&stats[co],      (double)s1);
            atomicAdd(&stats[CO + co], (double)s2);
        }
    }
}

// ---------------------------------------------------------------------------
__global__ void bnp_rC(const double* __restrict__ stats,
                       const float* __restrict__ g, const float* __restrict__ be,
                       float2* __restrict__ sc, int C, double invNL)
{
    int c = threadIdx.x;
    if (c >= C) return;
    double mu  = stats[c] * invNL;
    double var = stats[C + c] * invNL - mu * mu;
    double rs  = 1.0 / sqrt(var + 1e-5);
    double gv  = (double)g[c] * rs;
    double bv  = (double)be[c] - mu * gv;
    sc[c] = make_float2((float)gv, (float)bv);
}

__global__ __launch_bounds__(256)
void bna_rC(const float* __restrict__ x, const float2* __restrict__ sc,
            const float* __restrict__ addsrc, float* __restrict__ y,
            int C, int L, int relu, int n4)
{
    int i = blockIdx.x * 256 + threadIdx.x;
    if (i >= n4) return;
    int base = i * 4;
    int c = (base / L) % C;
    float2 s = sc[c];
    float4 xv = ((const float4*)x)[i];
    float4 r;
    r.x = xv.x * s.x + s.y;
    r.y = xv.y * s.x + s.y;
    r.z = xv.z * s.x + s.y;
    r.w = xv.w * s.x + s.y;
    if (relu) {
        r.x = fmaxf(r.x, 0.f); r.y = fmaxf(r.y, 0.f);
        r.z = fmaxf(r.z, 0.f); r.w = fmaxf(r.w, 0.f);
    }
    if (addsrc) {
        float4 av = ((const float4*)addsrc)[i];
        r.x += av.x; r.y += av.y; r.z += av.z; r.w += av.w;
    }
    ((float4*)y)[i] = r;
}

// ---------------------------------------------------------------------------
// VQ rC: 512 blocks x 256 thr; 64 rows/block, 4 lanes/row split over DIMS
// (16 dims/lane, registers). All lanes scan all codes; 16-dim partial
// subtract-form distances combined via 2 commutative xor-shuffles (all
// lanes identical d). Codebook chunks staged with padded stride 68 ->
// sub-lane b128 reads hit disjoint bank groups (conflict-free).
// ---------------------------------------------------------------------------
__global__ __launch_bounds__(256)
void vq_rC(const float* __restrict__ z, const float* __restrict__ emb,
           float* __restrict__ hq, double* __restrict__ lossAcc)
{
    __shared__ float ws[128 * 68];   // 34.8 KB
    const int tid = threadIdx.x;
    const int sub = tid & 3;
    const int r   = blockIdx.x * 64 + (tid >> 2);

    const float4* zp = (const float4*)(z + (size_t)r * 64 + sub * 16);
    float4 z0 = zp[0], z1 = zp[1], z2 = zp[2], z3 = zp[3];

    float best = 3.4e38f;
    int   bj   = 0;
    for (int c0 = 0; c0 < 512; c0 += 128) {
        __syncthreads();
        for (int i = tid; i < 128 * 16; i += 256) {
            int j = i >> 4, q = i & 15;
            ((float4*)ws)[j * 17 + q] = ((const float4*)(emb + c0 * 64))[i];
        }
        __syncthreads();
        for (int j = 0; j < 128; ++j) {
            const float4* wp = (const float4*)&ws[j * 68 + sub * 16];
            float4 w0 = wp[0], w1 = wp[1], w2 = wp[2], w3 = wp[3];
            float d = 0.f, t;
            t = z0.x - w0.x; d += t * t;  t = z0.y - w0.y; d += t * t;
            t = z0.z - w0.z; d += t * t;  t = z0.w - w0.w; d += t * t;
            t = z1.x - w1.x; d += t * t;  t = z1.y - w1.y; d += t * t;
            t = z1.z - w1.z; d += t * t;  t = z1.w - w1.w; d += t * t;
            t = z2.x - w2.x; d += t * t;  t = z2.y - w2.y; d += t * t;
            t = z2.z - w2.z; d += t * t;  t = z2.w - w2.w; d += t * t;
            t = z3.x - w3.x; d += t * t;  t = z3.y - w3.y; d += t * t;
            t = z3.z - w3.z; d += t * t;  t = z3.w - w3.w; d += t * t;
            // commutative combine -> all 4 lanes hold identical full d
            d += __shfl_xor(d, 1, 64);
            d += __shfl_xor(d, 2, 64);
            if (d < best) { best = d; bj = c0 + j; }
        }
    }

    // cooperative hq write: each lane writes its 16 dims of the chosen code
    const float4* ep = (const float4*)(emb + (size_t)bj * 64 + sub * 16);
    float4* hp = (float4*)(hq + (size_t)r * 64 + sub * 16);
    hp[0] = ep[0]; hp[1] = ep[1]; hp[2] = ep[2]; hp[3] = ep[3];

    // loss: one contribution per row
    float s = (sub == 0) ? best : 0.f;
#pragma unroll
    for (int m = 1; m < 64; m <<= 1) s += __shfl_xor(s, m, 64);
    if ((tid & 63) == 0) atomicAdd(lossAcc, (double)s);
}

__global__ void zd_rC(double* p, int n) {
    int i = blockIdx.x * 256 + threadIdx.x;
    if (i < n) p[i] = 0.0;
}

__global__ void wsguard_rC(float* p, int n) {
    int i = blockIdx.x * 256 + threadIdx.x;
    if (i < n) p[i] = 1000.0f;
}

__global__ void lossfin_rC(const double* acc, float* out) {
    float m = (float)(acc[0] * (1.0 / 32768.0));
    out[2097152] = m;   // commit_loss
    out[2097153] = m;   // vq_loss
}

extern "C" void kernel_launch(void* const* d_in, const int* in_sizes, int n_in,
                              void* d_out, int out_size, void* d_ws, size_t ws_size,
                              hipStream_t stream)
{
    const size_t NEED = (size_t)3 * 4194304 * 4 + 2305 * 8 + 1152 * 8 + 64;
    if (ws_size < NEED) {
        wsguard_rC<<<dim3((out_size + 255) / 256), 256, 0, stream>>>((float*)d_out, out_size);
        return;
    }

    const float* x        = (const float*)d_in[0];
    const float* w_conv   = (const float*)d_in[1];
    const float* b_conv   = (const float*)d_in[2];
    const float* g_conv   = (const float*)d_in[3];
    const float* be_conv  = (const float*)d_in[4];
    const float* w_r1     = (const float*)d_in[5];
    const float* b_r1     = (const float*)d_in[6];
    const float* g_r1     = (const float*)d_in[7];
    const float* be_r1    = (const float*)d_in[8];
    const float* w_ds1    = (const float*)d_in[9];
    const float* b_ds1    = (const float*)d_in[10];
    const float* w_r2     = (const float*)d_in[11];
    const float* b_r2     = (const float*)d_in[12];
    const float* g_r2     = (const float*)d_in[13];
    const float* be_r2    = (const float*)d_in[14];
    const float* w_1to2   = (const float*)d_in[15];
    const float* w_ds2    = (const float*)d_in[16];
    const float* b_ds2    = (const float*)d_in[17];
    const float* embed_w  = (const float*)d_in[18];
    const float* w_us2    = (const float*)d_in[19];
    const float* b_us2    = (const float*)d_in[20];
    const float* w_dr2    = (const float*)d_in[21];
    const float* b_dr2    = (const float*)d_in[22];
    const float* g_dr2    = (const float*)d_in[23];
    const float* be_dr2   = (const float*)d_in[24];
    const float* w_2to1   = (const float*)d_in[25];
    const float* w_us1    = (const float*)d_in[26];
    const float* b_us1    = (const float*)d_in[27];
    const float* w_dr1    = (const float*)d_in[28];
    const float* b_dr1    = (const float*)d_in[29];
    const float* g_dr1    = (const float*)d_in[30];
    const float* be_dr1   = (const float*)d_in[31];
    const float* w_deconv = (const float*)d_in[32];
    const float* b_deconv = (const float*)d_in[33];

    float* out = (float*)d_out;

    float*  B0 = (float*)d_ws;
    float*  B1 = B0 + 4194304;
    float*  B2 = B1 + 4194304;
    double* SD = (double*)(B2 + 4194304);
    double* lossAcc = SD + 9 * 256;
    float2* SC = (float2*)(SD + 2305);

    const int N = 64;
    const double i64k = 1.0 / 65536.0;
    const double i32k = 1.0 / 32768.0;

    zd_rC<<<dim3(10), 256, 0, stream>>>(SD, 9 * 256 + 1);

    // ---- encoder ----
    conv_rC<32,64,7,0,128,32, false,true,true,false>
        <<<dim3(8, N, 2), 256, 0, stream>>>(x, w_conv, b_conv, nullptr, SD+0*256, B0, 1024, 1024, 3);
    bnp_rC<<<1, 128, 0, stream>>>(SD+0*256, g_conv, be_conv, SC+0*128, 64, i64k);
    bna_rC<<<dim3(4096), 256, 0, stream>>>(B0, SC+0*128, nullptr, B0, 64, 1024, 0, 1048576);

    conv_rC<64,64,3,0,128,32, false,true,true,false>
        <<<dim3(8, N, 2), 256, 0, stream>>>(B0, w_r1, b_r1, nullptr, SD+1*256, B1, 1024, 1024, 1);
    bnp_rC<<<1, 128, 0, stream>>>(SD+1*256, g_r1, be_r1, SC+1*128, 64, i64k);
    bna_rC<<<dim3(4096), 256, 0, stream>>>(B1, SC+1*128, nullptr, B1, 64, 1024, 1, 1048576);

    conv_rC<64,64,3,0,128,32, false,true,true,false>
        <<<dim3(8, N, 2), 256, 0, stream>>>(B1, w_r1+12288, b_r1+64, nullptr, SD+2*256, B2, 1024, 1024, 1);
    bnp_rC<<<1, 128, 0, stream>>>(SD+2*256, g_r1+64, be_r1+64, SC+2*128, 64, i64k);
    bna_rC<<<dim3(4096), 256, 0, stream>>>(B2, SC+2*128, nullptr, B2, 64, 1024, 1, 1048576);

    conv_rC<64,64,3,0,128,32, false,true,true,false>
        <<<dim3(8, N, 2), 256, 0, stream>>>(B2, w_r1+24576, b_r1+128, nullptr, SD+3*256, B1, 1024, 1024, 1);
    bnp_rC<<<1, 128, 0, stream>>>(SD+3*256, g_r1+128, be_r1+128, SC+3*128, 64, i64k);
    bna_rC<<<dim3(4096), 256, 0, stream>>>(B1, SC+3*128, B0, B0, 64, 1024, 0, 1048576);

    conv_rC<64,64,2,1,64,32, false,false,true,false>
        <<<dim3(8, N, 2), 256, 0, stream>>>(B0, w_ds1, b_ds1, nullptr, nullptr, B1, 1024, 512, 0);

    conv_rC<64,128,3,0,128,32, false,true,true,false>
        <<<dim3(4, N, 4), 256, 0, stream>>>(B1, w_r2, b_r2, nullptr, SD+4*256, B2, 512, 512, 1);
    bnp_rC<<<1, 128, 0, stream>>>(SD+4*256, g_r2, be_r2, SC+4*128, 128, i32k);
    bna_rC<<<dim3(4096), 256, 0, stream>>>(B2, SC+4*128, nullptr, B2, 128, 512, 0, 1048576);

    conv_rC<64,128,1,0,128,32, false,false,false,true>
        <<<dim3(4, N, 4), 256, 0, stream>>>(B1, w_1to2, nullptr, B2, nullptr, B0, 512, 512, 0);

    conv_rC<128,128,2,1,32,16, false,false,true,false>
        <<<dim3(8, N, 8), 256, 0, stream>>>(B0, w_ds2, b_ds2, nullptr, nullptr, B1, 512, 256, 0);

    // ---- vector quantization ----
    vq_rC<<<dim3(512), 256, 0, stream>>>(B1, embed_w, B2, lossAcc);
    lossfin_rC<<<1, 1, 0, stream>>>(lossAcc, out);

    // ---- decoder ----
    conv_rC<128,128,2,2,64,32, false,false,true,false>
        <<<dim3(8, N, 4), 256, 0, stream>>>(B2, w_us2, b_us2, nullptr, nullptr, B0, 256, 512, 0);

    conv_rC<128,64,3,0,64,16, true,true,true,false>
        <<<dim3(8, N, 4), 256, 0, stream>>>(B0, w_dr2, b_dr2, nullptr, SD+5*256, B1, 512, 512, 1);
    bnp_rC<<<1, 128, 0, stream>>>(SD+5*256, g_dr2, be_dr2, SC+5*128, 64, i32k);
    bna_rC<<<dim3(2048), 256, 0, stream>>>(B1, SC+5*128, nullptr, B1, 64, 512, 0, 524288);

    conv_rC<128,64,1,0,64,32, false,false,false,true>
        <<<dim3(8, N, 2), 256, 0, stream>>>(B0, w_2to1, nullptr, B1, nullptr, B2, 512, 512, 0);

    conv_rC<64,64,2,2,128,32, false,false,true,false>
        <<<dim3(8, N, 2), 256, 0, stream>>>(B2, w_us1, b_us1, nullptr, nullptr, B0, 512, 1024, 0);

    conv_rC<64,64,3,0,128,32, true,true,true,false>
        <<<dim3(8, N, 2), 256, 0, stream>>>(B0, w_dr1, b_dr1, nullptr, SD+6*256, B1, 1024, 1024, 1);
    bnp_rC<<<1, 128, 0, stream>>>(SD+6*256, g_dr1, be_dr1, SC+6*128, 64, i64k);
    bna_rC<<<dim3(4096), 256, 0, stream>>>(B1, SC+6*128, nullptr, B1, 64, 1024, 1, 1048576);

    conv_rC<64,64,3,0,128,32, true,true,true,false>
        <<<dim3(8, N, 2), 256, 0, stream>>>(B1, w_dr1+12288, b_dr1+64, nullptr, SD+7*256, B2, 1024, 1024, 1);
    bnp_rC<<<1, 128, 0, stream>>>(SD+7*256, g_dr1+64, be_dr1+64, SC+7*128, 64, i64k);
    bna_rC<<<dim3(4096), 256, 0, stream>>>(B2, SC+7*128, nullptr, B2, 64, 1024, 1, 1048576);

    conv_rC<64,64,3,0,128,32, true,true,true,false>
        <<<dim3(8, N, 2), 256, 0, stream>>>(B2, w_dr1+24576, b_dr1+128, nullptr, SD+8*256, B1, 1024, 1024, 1);
    bnp_rC<<<1, 128, 0, stream>>>(SD+8*256, g_dr1+128, be_dr1+128, SC+8*128, 64, i64k);
    bna_rC<<<dim3(4096), 256, 0, stream>>>(B1, SC+8*128, B0, B0, 64, 1024, 0, 1048576);

    conv_rC<64,32,7,0,128,16, true,false,true,false>
        <<<dim3(8, N, 2), 256, 0, stream>>>(B0, w_deconv, b_deconv, nullptr, nullptr, out, 1024, 1024, 3);
}

// Round 13
// 1395.833 us; speedup vs baseline: 1.1058x; 1.1058x over previous
//
// ===========================================================================
// R13 — best-of-both: R11 conv geometry (TL=64, TLT=8 -> stride-8 2-way-free
// LDS reads, 42 KB -> 3 blocks/CU) + R12 VQ (dims-split lanes, padded
// stride-68 codebook, conflict-free). Numerics identical to R12 kernels.
// ===========================================================================
#include <hip/hip_runtime.h>
#include <hip/hip_bf16.h>
#include <stdint.h>

// ---------------------------------------------------------------------------
// Tiled conv. MODE 0: stride-1 (pad runtime), WT=true: ConvTranspose (I,O,K)
// flipped. MODE 1: stride-2 downsample K=2. MODE 2: stride-2 transposed
// upsample K=2. Block: 256 thr = COB co x LT(=256/COB) l-groups, TLT=TL/LT
// outputs/thread. Per-output accumulation: ci-major, k-inner.
// ---------------------------------------------------------------------------
template<int CI, int CO, int K, int MODE, int TL, int COB,
         bool WT, bool STATS, bool HAS_BIAS, bool HAS_ADD>
__global__ __launch_bounds__(256)
void conv_rD(const float* __restrict__ xin,
             const float* __restrict__ w,
             const float* __restrict__ bias,
             const float* __restrict__ addsrc,
             double* __restrict__ stats,
             float* __restrict__ yout,
             int Lin, int Lout, int pad)
{
    constexpr int LT   = 256 / COB;
    constexpr int TLT  = TL / LT;
    constexpr int SPAN = (MODE == 0) ? (TL + K - 1)
                       : (MODE == 1) ? ((TL - 1) * 2 + K)
                       : (TL / 2);
    constexpr int SPANP = (SPAN + 3) & ~3;
    constexpr int WN    = COB * CI * K;

    __shared__ float xs[CI * SPANP];
    __shared__ float wl[WN];   // [ci][k][co_l]

    const int tid    = threadIdx.x;
    const int ltile  = blockIdx.x;
    const int n      = blockIdx.y;
    const int coBase = blockIdx.z * COB;

    for (int i = tid; i < WN; i += 256) {
        int ci   = i / (K * COB);
        int rem  = i - ci * (K * COB);
        int k    = rem / COB;
        int co_l = rem - k * COB;
        int co   = coBase + co_l;
        int src;
        if (WT)             src = (ci * CO + co) * K + (K - 1 - k);
        else if (MODE == 2) src = (ci * CO + co) * K + k;
        else                src = (co * CI + ci) * K + k;
        wl[i] = w[src];
    }

    int x0;
    if (MODE == 0)      x0 = ltile * TL - pad;
    else if (MODE == 1) x0 = ltile * TL * 2;
    else                x0 = ltile * (TL / 2);
    for (int i = tid; i < CI * SPAN; i += 256) {
        int ci = i / SPAN;
        int s  = i - ci * SPAN;
        int xl = x0 + s;
        float v = 0.f;
        if (xl >= 0 && xl < Lin) v = xin[((size_t)n * CI + ci) * Lin + xl];
        xs[ci * SPANP + s] = v;
    }
    __syncthreads();

    const int co_l  = tid / LT;
    const int co    = coBase + co_l;
    const int loOff = (tid % LT) * TLT;

    float acc[TLT];
#pragma unroll
    for (int j = 0; j < TLT; ++j) acc[j] = HAS_BIAS ? bias[co] : 0.f;

    constexpr int XR = (MODE == 0) ? (TLT + K - 1)
                     : (MODE == 1) ? ((TLT - 1) * 2 + K)
                     : (TLT / 2);

    for (int ci = 0; ci < CI; ++ci) {
        float xr[XR];
        const int xb = ci * SPANP + ((MODE == 1) ? loOff * 2
                                   : (MODE == 2) ? (loOff / 2) : loOff);
#pragma unroll
        for (int t = 0; t < XR; ++t) xr[t] = xs[xb + t];
        if (MODE == 2) {
            float w0 = wl[(ci * 2 + 0) * COB + co_l];
            float w1 = wl[(ci * 2 + 1) * COB + co_l];
#pragma unroll
            for (int j = 0; j < TLT; ++j)
                acc[j] += ((j & 1) ? w1 : w0) * xr[j >> 1];
        } else {
#pragma unroll
            for (int k = 0; k < K; ++k) {
                float wk = wl[(ci * K + k) * COB + co_l];
#pragma unroll
                for (int j = 0; j < TLT; ++j)
                    acc[j] += wk * xr[((MODE == 1) ? 2 * j : j) + k];
            }
        }
    }

    const int lo0   = ltile * TL + loOff;
    const size_t obase = ((size_t)n * CO + co) * Lout + lo0;

    if (HAS_ADD) {
#pragma unroll
        for (int j = 0; j < TLT; ++j) acc[j] += addsrc[obase + j];
    }

#pragma unroll
    for (int j = 0; j < TLT; ++j) yout[obase + j] = acc[j];

    if (STATS) {
        float s1 = 0.f, s2 = 0.f;
#pragma unroll
        for (int j = 0; j < TLT; ++j) { s1 += acc[j]; s2 += acc[j] * acc[j]; }
#pragma unroll
        for (int m = 1; m < LT; m <<= 1) {
            s1 += __shfl_xor(s1, m, 64);
            s2 += __shfl_xor(s2, m, 64);
        }
        if ((tid & (LT - 1)) == 0) {
            atomicAdd(&stats[co],      (double)s1);
            atomicAdd(&stats[CO + co], (double)s2);
        }
    }
}

// ---------------------------------------------------------------------------
__global__ void bnp_rD(const double* __restrict__ stats,
                       const float* __restrict__ g, const float* __restrict__ be,
                       float2* __restrict__ sc, int C, double invNL)
{
    int c = threadIdx.x;
    if (c >= C) return;
    double mu  = stats[c] * invNL;
    double var = stats[C + c] * invNL - mu * mu;
    double rs  = 1.0 / sqrt(var + 1e-5);
    double gv  = (double)g[c] * rs;
    double bv  = (double)be[c] - mu * gv;
    sc[c] = make_float2((float)gv, (float)bv);
}

__global__ __launch_bounds__(256)
void bna_rD(const float* __restrict__ x, const float2* __restrict__ sc,
            const float* __restrict__ addsrc, float* __restrict__ y,
            int C, int L, int relu, int n4)
{
    int i = blockIdx.x * 256 + threadIdx.x;
    if (i >= n4) return;
    int base = i * 4;
    int c = (base / L) % C;
    float2 s = sc[c];
    float4 xv = ((const float4*)x)[i];
    float4 r;
    r.x = xv.x * s.x + s.y;
    r.y = xv.y * s.x + s.y;
    r.z = xv.z * s.x + s.y;
    r.w = xv.w * s.x + s.y;
    if (relu) {
        r.x = fmaxf(r.x, 0.f); r.y = fmaxf(r.y, 0.f);
        r.z = fmaxf(r.z, 0.f); r.w = fmaxf(r.w, 0.f);
    }
    if (addsrc) {
        float4 av = ((const float4*)addsrc)[i];
        r.x += av.x; r.y += av.y; r.z += av.z; r.w += av.w;
    }
    ((float4*)y)[i] = r;
}

// ---------------------------------------------------------------------------
// VQ (R12's): 512 blocks x 256 thr; 64 rows/block, 4 lanes/row split over
// dims (16/lane in regs). Padded codebook stride 68 -> conflict-free b128.
// Commutative cross-lane combine -> identical d on all 4 lanes.
// ---------------------------------------------------------------------------
__global__ __launch_bounds__(256)
void vq_rD(const float* __restrict__ z, const float* __restrict__ emb,
           float* __restrict__ hq, double* __restrict__ lossAcc)
{
    __shared__ float ws[128 * 68];
    const int tid = threadIdx.x;
    const int sub = tid & 3;
    const int r   = blockIdx.x * 64 + (tid >> 2);

    const float4* zp = (const float4*)(z + (size_t)r * 64 + sub * 16);
    float4 z0 = zp[0], z1 = zp[1], z2 = zp[2], z3 = zp[3];

    float best = 3.4e38f;
    int   bj   = 0;
    for (int c0 = 0; c0 < 512; c0 += 128) {
        __syncthreads();
        for (int i = tid; i < 128 * 16; i += 256) {
            int j = i >> 4, q = i & 15;
            ((float4*)ws)[j * 17 + q] = ((const float4*)(emb + c0 * 64))[i];
        }
        __syncthreads();
        for (int j = 0; j < 128; ++j) {
            const float4* wp = (const float4*)&ws[j * 68 + sub * 16];
            float4 w0 = wp[0], w1 = wp[1], w2 = wp[2], w3 = wp[3];
            float d = 0.f, t;
            t = z0.x - w0.x; d += t * t;  t = z0.y - w0.y; d += t * t;
            t = z0.z - w0.z; d += t * t;  t = z0.w - w0.w; d += t * t;
            t = z1.x - w1.x; d += t * t;  t = z1.y - w1.y; d += t * t;
            t = z1.z - w1.z; d += t * t;  t = z1.w - w1.w; d += t * t;
            t = z2.x - w2.x; d += t * t;  t = z2.y - w2.y; d += t * t;
            t = z2.z - w2.z; d += t * t;  t = z2.w - w2.w; d += t * t;
            t = z3.x - w3.x; d += t * t;  t = z3.y - w3.y; d += t * t;
            t = z3.z - w3.z; d += t * t;  t = z3.w - w3.w; d += t * t;
            d += __shfl_xor(d, 1, 64);
            d += __shfl_xor(d, 2, 64);
            if (d < best) { best = d; bj = c0 + j; }
        }
    }

    const float4* ep = (const float4*)(emb + (size_t)bj * 64 + sub * 16);
    float4* hp = (float4*)(hq + (size_t)r * 64 + sub * 16);
    hp[0] = ep[0]; hp[1] = ep[1]; hp[2] = ep[2]; hp[3] = ep[3];

    float s = (sub == 0) ? best : 0.f;
#pragma unroll
    for (int m = 1; m < 64; m <<= 1) s += __shfl_xor(s, m, 64);
    if ((tid & 63) == 0) atomicAdd(lossAcc, (double)s);
}

__global__ void zd_rD(double* p, int n) {
    int i = blockIdx.x * 256 + threadIdx.x;
    if (i < n) p[i] = 0.0;
}

__global__ void wsguard_rD(float* p, int n) {
    int i = blockIdx.x * 256 + threadIdx.x;
    if (i < n) p[i] = 1000.0f;
}

__global__ void lossfin_rD(const double* acc, float* out) {
    float m = (float)(acc[0] * (1.0 / 32768.0));
    out[2097152] = m;   // commit_loss
    out[2097153] = m;   // vq_loss
}

extern "C" void kernel_launch(void* const* d_in, const int* in_sizes, int n_in,
                              void* d_out, int out_size, void* d_ws, size_t ws_size,
                              hipStream_t stream)
{
    const size_t NEED = (size_t)3 * 4194304 * 4 + 2305 * 8 + 1152 * 8 + 64;
    if (ws_size < NEED) {
        wsguard_rD<<<dim3((out_size + 255) / 256), 256, 0, stream>>>((float*)d_out, out_size);
        return;
    }

    const float* x        = (const float*)d_in[0];
    const float* w_conv   = (const float*)d_in[1];
    const float* b_conv   = (const float*)d_in[2];
    const float* g_conv   = (const float*)d_in[3];
    const float* be_conv  = (const float*)d_in[4];
    const float* w_r1     = (const float*)d_in[5];
    const float* b_r1     = (const float*)d_in[6];
    const float* g_r1     = (const float*)d_in[7];
    const float* be_r1    = (const float*)d_in[8];
    const float* w_ds1    = (const float*)d_in[9];
    const float* b_ds1    = (const float*)d_in[10];
    const float* w_r2     = (const float*)d_in[11];
    const float* b_r2     = (const float*)d_in[12];
    const float* g_r2     = (const float*)d_in[13];
    const float* be_r2    = (const float*)d_in[14];
    const float* w_1to2   = (const float*)d_in[15];
    const float* w_ds2    = (const float*)d_in[16];
    const float* b_ds2    = (const float*)d_in[17];
    const float* embed_w  = (const float*)d_in[18];
    const float* w_us2    = (const float*)d_in[19];
    const float* b_us2    = (const float*)d_in[20];
    const float* w_dr2    = (const float*)d_in[21];
    const float* b_dr2    = (const float*)d_in[22];
    const float* g_dr2    = (const float*)d_in[23];
    const float* be_dr2   = (const float*)d_in[24];
    const float* w_2to1   = (const float*)d_in[25];
    const float* w_us1    = (const float*)d_in[26];
    const float* b_us1    = (const float*)d_in[27];
    const float* w_dr1    = (const float*)d_in[28];
    const float* b_dr1    = (const float*)d_in[29];
    const float* g_dr1    = (const float*)d_in[30];
    const float* be_dr1   = (const float*)d_in[31];
    const float* w_deconv = (const float*)d_in[32];
    const float* b_deconv = (const float*)d_in[33];

    float* out = (float*)d_out;

    float*  B0 = (float*)d_ws;
    float*  B1 = B0 + 4194304;
    float*  B2 = B1 + 4194304;
    double* SD = (double*)(B2 + 4194304);
    double* lossAcc = SD + 9 * 256;
    float2* SC = (float2*)(SD + 2305);

    const int N = 64;
    const double i64k = 1.0 / 65536.0;
    const double i32k = 1.0 / 32768.0;

    zd_rD<<<dim3(10), 256, 0, stream>>>(SD, 9 * 256 + 1);

    // ---- encoder ----
    conv_rD<32,64,7,0,64,32, false,true,true,false>
        <<<dim3(16, N, 2), 256, 0, stream>>>(x, w_conv, b_conv, nullptr, SD+0*256, B0, 1024, 1024, 3);
    bnp_rD<<<1, 128, 0, stream>>>(SD+0*256, g_conv, be_conv, SC+0*128, 64, i64k);
    bna_rD<<<dim3(4096), 256, 0, stream>>>(B0, SC+0*128, nullptr, B0, 64, 1024, 0, 1048576);

    conv_rD<64,64,3,0,64,32, false,true,true,false>
        <<<dim3(16, N, 2), 256, 0, stream>>>(B0, w_r1, b_r1, nullptr, SD+1*256, B1, 1024, 1024, 1);
    bnp_rD<<<1, 128, 0, stream>>>(SD+1*256, g_r1, be_r1, SC+1*128, 64, i64k);
    bna_rD<<<dim3(4096), 256, 0, stream>>>(B1, SC+1*128, nullptr, B1, 64, 1024, 1, 1048576);

    conv_rD<64,64,3,0,64,32, false,true,true,false>
        <<<dim3(16, N, 2), 256, 0, stream>>>(B1, w_r1+12288, b_r1+64, nullptr, SD+2*256, B2, 1024, 1024, 1);
    bnp_rD<<<1, 128, 0, stream>>>(SD+2*256, g_r1+64, be_r1+64, SC+2*128, 64, i64k);
    bna_rD<<<dim3(4096), 256, 0, stream>>>(B2, SC+2*128, nullptr, B2, 64, 1024, 1, 1048576);

    conv_rD<64,64,3,0,64,32, false,true,true,false>
        <<<dim3(16, N, 2), 256, 0, stream>>>(B2, w_r1+24576, b_r1+128, nullptr, SD+3*256, B1, 1024, 1024, 1);
    bnp_rD<<<1, 128, 0, stream>>>(SD+3*256, g_r1+128, be_r1+128, SC+3*128, 64, i64k);
    bna_rD<<<dim3(4096), 256, 0, stream>>>(B1, SC+3*128, B0, B0, 64, 1024, 0, 1048576);

    conv_rD<64,64,2,1,32,32, false,false,true,false>
        <<<dim3(16, N, 2), 256, 0, stream>>>(B0, w_ds1, b_ds1, nullptr, nullptr, B1, 1024, 512, 0);

    conv_rD<64,128,3,0,64,32, false,true,true,false>
        <<<dim3(8, N, 4), 256, 0, stream>>>(B1, w_r2, b_r2, nullptr, SD+4*256, B2, 512, 512, 1);
    bnp_rD<<<1, 128, 0, stream>>>(SD+4*256, g_r2, be_r2, SC+4*128, 128, i32k);
    bna_rD<<<dim3(4096), 256, 0, stream>>>(B2, SC+4*128, nullptr, B2, 128, 512, 0, 1048576);

    conv_rD<64,128,1,0,64,32, false,false,false,true>
        <<<dim3(8, N, 4), 256, 0, stream>>>(B1, w_1to2, nullptr, B2, nullptr, B0, 512, 512, 0);

    conv_rD<128,128,2,1,32,16, false,false,true,false>
        <<<dim3(8, N, 8), 256, 0, stream>>>(B0, w_ds2, b_ds2, nullptr, nullptr, B1, 512, 256, 0);

    // ---- vector quantization ----
    vq_rD<<<dim3(512), 256, 0, stream>>>(B1, embed_w, B2, lossAcc);
    lossfin_rD<<<1, 1, 0, stream>>>(lossAcc, out);

    // ---- decoder ----
    conv_rD<128,128,2,2,64,32, false,false,true,false>
        <<<dim3(8, N, 4), 256, 0, stream>>>(B2, w_us2, b_us2, nullptr, nullptr, B0, 256, 512, 0);

    conv_rD<128,64,3,0,64,16, true,true,true,false>
        <<<dim3(8, N, 4), 256, 0, stream>>>(B0, w_dr2, b_dr2, nullptr, SD+5*256, B1, 512, 512, 1);
    bnp_rD<<<1, 128, 0, stream>>>(SD+5*256, g_dr2, be_dr2, SC+5*128, 64, i32k);
    bna_rD<<<dim3(2048), 256, 0, stream>>>(B1, SC+5*128, nullptr, B1, 64, 512, 0, 524288);

    conv_rD<128,64,1,0,64,32, false,false,false,true>
        <<<dim3(8, N, 2), 256, 0, stream>>>(B0, w_2to1, nullptr, B1, nullptr, B2, 512, 512, 0);

    conv_rD<64,64,2,2,64,32, false,false,true,false>
        <<<dim3(16, N, 2), 256, 0, stream>>>(B2, w_us1, b_us1, nullptr, nullptr, B0, 512, 1024, 0);

    conv_rD<64,64,3,0,64,32, true,true,true,false>
        <<<dim3(16, N, 2), 256, 0, stream>>>(B0, w_dr1, b_dr1, nullptr, SD+6*256, B1, 1024, 1024, 1);
    bnp_rD<<<1, 128, 0, stream>>>(SD+6*256, g_dr1, be_dr1, SC+6*128, 64, i64k);
    bna_rD<<<dim3(4096), 256, 0, stream>>>(B1, SC+6*128, nullptr, B1, 64, 1024, 1, 1048576);

    conv_rD<64,64,3,0,64,32, true,true,true,false>
        <<<dim3(16, N, 2), 256, 0, stream>>>(B1, w_dr1+12288, b_dr1+64, nullptr, SD+7*256, B2, 1024, 1024, 1);
    bnp_rD<<<1, 128, 0, stream>>>(SD+7*256, g_dr1+64, be_dr1+64, SC+7*128, 64, i64k);
    bna_rD<<<dim3(4096), 256, 0, stream>>>(B2, SC+7*128, nullptr, B2, 64, 1024, 1, 1048576);

    conv_rD<64,64,3,0,64,32, true,true,true,false>
        <<<dim3(16, N, 2), 256, 0, stream>>>(B2, w_dr1+24576, b_dr1+128, nullptr, SD+8*256, B1, 1024, 1024, 1);
    bnp_rD<<<1, 128, 0, stream>>>(SD+8*256, g_dr1+128, be_dr1+128, SC+8*128, 64, i64k);
    bna_rD<<<dim3(4096), 256, 0, stream>>>(B1, SC+8*128, B0, B0, 64, 1024, 0, 1048576);

    conv_rD<64,32,7,0,64,16, true,false,true,false>
        <<<dim3(16, N, 2), 256, 0, stream>>>(B0, w_deconv, b_deconv, nullptr, nullptr, out, 1024, 1024, 3);
}